// Round 1
// 554.532 us; speedup vs baseline: 1.8466x; 1.8466x over previous
//
#include <hip/hip_runtime.h>
#include <math.h>

#define TWO_PI 6.28318530717958647692f

typedef __attribute__((ext_vector_type(8))) short bf16x8;
typedef __attribute__((ext_vector_type(4))) float f32x4;
typedef __attribute__((ext_vector_type(4))) short short4v;

#define MFMA16(A,B,C) __builtin_amdgcn_mfma_f32_16x16x32_bf16((A),(B),(C),0,0,0)

// Problem: B=16, C=64, H=W=256, M1=M2=32. Kept rows f = s<32 ? s : s+192, cols k2<32.
// Pipeline (all matmuls on MFMA, hi/lo-split bf16, fp32 accum):
//   fwd : Yw = x @ B2 (w-DFT), X = E1c @ Yw (h-DFT)           -> X[img][64][64] (Re|Im)
//   inv : G = X*wsum ; T = [C|S] @ [[Gr,Gi],[-Gi,Gr]] ; out = [Tr|Ti] @ D
// Constants are PRE-FRAGMENTED in MFMA lane order (16B load per fragment).

// const region offsets in shorts (hi then lo per matrix)
#define C_B2H 0          // B-op 256x64   (8 kt x 4 nt)
#define C_B2L 16384
#define C_C1H 32768      // A-op 64x256   (4 mt x 8 kt)  cos(f h)
#define C_C1L 49152
#define C_S1H 65536      //               sin(f h)
#define C_S1L 81920
#define C_SNH 98304      //              -sin(f h)
#define C_SNL 114688
#define C_A1H 131072     // A-op 256x128  (16 mt x 4 kt) [C | S]
#define C_A1L 163840
#define C_DH  196608     // B-op 64x256   (2 kt x 16 nt) [a cos ; -a sin]
#define C_DL  212992

__device__ __forceinline__ unsigned short bhi(float v) {
    union { float f; unsigned u; } x; x.f = v;
    return (unsigned short)(x.u >> 16);
}
__device__ __forceinline__ float bval(unsigned short h) {
    union { unsigned u; float f; } x; x.u = ((unsigned)h) << 16;
    return x.f;
}
__device__ __forceinline__ void split2(float v, unsigned short& hi, unsigned short& lo) {
    hi = bhi(v);
    lo = bhi(v - bval(hi));
}

// ---------------------------------------------------------------------------
// Setup: twiddle matrices, pre-fragmented + hi/lo split. 114688 value slots.
// ---------------------------------------------------------------------------
__global__ __launch_bounds__(256)
void const_kernel(unsigned short* __restrict__ cst) {
    int e = blockIdx.x * 256 + threadIdx.x;
    const float w0 = TWO_PI / 256.0f;
    float v; int i, baseH, baseL;
    if (e < 16384) {                        // B2: [cos(k2 w) | -sin(k2 w)]
        i = e; baseH = C_B2H; baseL = C_B2L;
        int j = i & 7, lane = (i >> 3) & 63, tt = i >> 9;
        int nt = tt & 3, kt = tt >> 2;
        int k = kt * 32 + (lane >> 4) * 8 + j;       // w
        int n = nt * 16 + (lane & 15);
        int fr = n & 31;
        float s_, c_;
        sincosf(w0 * (float)((fr * k) & 255), &s_, &c_);
        v = (n < 32) ? c_ : -s_;
    } else if (e < 65536) {                 // C1 / S1 / -S1 over (s,h)
        int mid = (e - 16384) >> 14;
        i = (e - 16384) & 16383;
        baseH = C_C1H + mid * 32768; baseL = baseH + 16384;
        int j = i & 7, lane = (i >> 3) & 63, tt = i >> 9;
        int mt = tt & 3, kt = tt >> 2;
        int s = mt * 16 + (lane & 15);
        int h = kt * 32 + (lane >> 4) * 8 + j;
        int f = (s < 32) ? s : s + 192;
        float s_, c_;
        sincosf(w0 * (float)((f * h) & 255), &s_, &c_);
        v = (mid == 0) ? c_ : ((mid == 1) ? s_ : -s_);
    } else if (e < 98304) {                 // A1: [C(h,s) | S(h,s)]
        i = e - 65536; baseH = C_A1H; baseL = C_A1L;
        int j = i & 7, lane = (i >> 3) & 63, tt = i >> 9;
        int mt = tt & 15, kt = tt >> 4;
        int h = mt * 16 + (lane & 15);
        int k = kt * 32 + (lane >> 4) * 8 + j;
        int s = k & 63;
        int f = (s < 32) ? s : s + 192;
        float s_, c_;
        sincosf(w0 * (float)((f * h) & 255), &s_, &c_);
        v = (k < 64) ? c_ : s_;
    } else {                                // D: [a cos(k2 w) ; -a sin(k2 w)], a = 1 if k2==0 else 2
        i = e - 98304; baseH = C_DH; baseL = C_DL;
        int j = i & 7, lane = (i >> 3) & 63, tt = i >> 9;
        int nt = tt & 15, kt = tt >> 4;
        int wc = nt * 16 + (lane & 15);
        int k = kt * 32 + (lane >> 4) * 8 + j;
        int k2 = k & 31;
        float a = (k2 == 0) ? 1.f : 2.f;
        float s_, c_;
        sincosf(w0 * (float)((k2 * wc) & 255), &s_, &c_);
        v = (k < 32) ? a * c_ : -a * s_;
    }
    unsigned short hi, lo; split2(v, hi, lo);
    cst[baseH + i] = hi;
    cst[baseL + i] = lo;
}

// ---------------------------------------------------------------------------
// wsum[c,m1,m2] = (1/65536) * sum_j (w_r + i w_i)[j,c,m1,m2]   (unchanged)
// ---------------------------------------------------------------------------
__global__ __launch_bounds__(256)
void wsum_kernel(const float* __restrict__ w1r, const float* __restrict__ w1i,
                 const float* __restrict__ w2r, const float* __restrict__ w2i,
                 float2* __restrict__ s1, float2* __restrict__ s2) {
    int e = blockIdx.x * 256 + threadIdx.x;
    float a = 0.f, b = 0.f, c = 0.f, d = 0.f;
    #pragma unroll 4
    for (int j = 0; j < 64; ++j) {
        int idx = j * 65536 + e;
        a += w1r[idx]; b += w1i[idx];
        c += w2r[idx]; d += w2i[idx];
    }
    const float sc = 1.0f / 65536.0f;
    s1[e] = make_float2(a * sc, b * sc);
    s2[e] = make_float2(c * sc, d * sc);
}

// ---------------------------------------------------------------------------
// Forward: per image. X[s][n] (n<32 Re, n>=32 Im), fp32.
//   chunk 32 h-rows: xc -> LDS split; Ywc = xc @ B2 (MFMA); Ywc -> YT (transposed,
//   split); X += C1@Yr + S1@Yi (Re) / C1@Yi - S1@Yr (Im) with kt = chunk.
// ---------------------------------------------------------------------------
__global__ __launch_bounds__(256)
void fwd_kernel(const float* __restrict__ x, float* __restrict__ X,
                const unsigned short* __restrict__ cst) {
    const int img = blockIdx.x;
    const int t = threadIdx.x;
    const int lane = t & 63;
    const int wv = t >> 6;

    __shared__ unsigned short xs_hi[8192], xs_lo[8192];  // [32][256] swizzled
    __shared__ unsigned short yt_hi[2048], yt_lo[2048];  // [64][32]  swizzled

    f32x4 acc[4];
    #pragma unroll
    for (int i = 0; i < 4; ++i) { acc[i].x = 0; acc[i].y = 0; acc[i].z = 0; acc[i].w = 0; }

    const int mt2  = wv >> 1;          // stage-A tile row (both tiles share it)
    const int nt2b = (wv & 1) * 2;     // stage-A tile col base

    const float* xim = x + (size_t)img * 65536;
    const int r_st  = t >> 3;
    const int c4_st = t & 7;

    #pragma unroll 1
    for (int hc = 0; hc < 8; ++hc) {
        {   // stage 32 x-rows -> LDS (split bf16, row-swizzle)
            const float4* src = (const float4*)(xim + (size_t)(hc * 32 + r_st) * 256) + c4_st;
            #pragma unroll
            for (int i = 0; i < 8; ++i) {
                float4 vx = src[i * 8];
                int cc = (c4_st + i * 8) * 4;
                int idx = (r_st * 256 + cc) ^ ((r_st & 7) << 3);
                unsigned short h0,l0,h1,l1,h2,l2,h3,l3;
                split2(vx.x, h0, l0); split2(vx.y, h1, l1);
                split2(vx.z, h2, l2); split2(vx.w, h3, l3);
                short4v vh, vl;
                vh.x=(short)h0; vh.y=(short)h1; vh.z=(short)h2; vh.w=(short)h3;
                vl.x=(short)l0; vl.y=(short)l1; vl.z=(short)l2; vl.w=(short)l3;
                *(short4v*)&xs_hi[idx] = vh;
                *(short4v*)&xs_lo[idx] = vl;
            }
        }
        __syncthreads();
        // stage A: Ywc(32x64) = xc @ B2, 2 tiles/wave
        f32x4 acc2[2];
        acc2[0].x=0; acc2[0].y=0; acc2[0].z=0; acc2[0].w=0;
        acc2[1].x=0; acc2[1].y=0; acc2[1].z=0; acc2[1].w=0;
        {
            const int mrow = mt2 * 16 + (lane & 15);
            const int kb = (lane >> 4) * 8;
            #pragma unroll
            for (int kt = 0; kt < 8; ++kt) {
                int aidx = (mrow * 256 + kt * 32 + kb) ^ ((mrow & 7) << 3);
                bf16x8 ah = *(const bf16x8*)&xs_hi[aidx];
                bf16x8 al = *(const bf16x8*)&xs_lo[aidx];
                #pragma unroll
                for (int q = 0; q < 2; ++q) {
                    int boff = ((kt * 4 + nt2b + q) * 64 + lane) * 8;
                    bf16x8 bh = *(const bf16x8*)&cst[C_B2H + boff];
                    bf16x8 bl = *(const bf16x8*)&cst[C_B2L + boff];
                    acc2[q] = MFMA16(ah, bh, acc2[q]);
                    acc2[q] = MFMA16(ah, bl, acc2[q]);
                    acc2[q] = MFMA16(al, bh, acc2[q]);
                }
            }
        }
        {   // Ywc -> YT[n][h'] (transposed, split); pack 4 rows per b64 write
            const int hbase = mt2 * 16 + (lane >> 4) * 4;
            #pragma unroll
            for (int q = 0; q < 2; ++q) {
                int n = (nt2b + q) * 16 + (lane & 15);
                int idx = (n * 32 + hbase) ^ ((n & 7) << 3);
                short4v vh, vl; unsigned short hh, ll;
                split2(acc2[q][0], hh, ll); vh.x=(short)hh; vl.x=(short)ll;
                split2(acc2[q][1], hh, ll); vh.y=(short)hh; vl.y=(short)ll;
                split2(acc2[q][2], hh, ll); vh.z=(short)hh; vl.z=(short)ll;
                split2(acc2[q][3], hh, ll); vh.w=(short)hh; vl.w=(short)ll;
                *(short4v*)&yt_hi[idx] = vh;
                *(short4v*)&yt_lo[idx] = vl;
            }
        }
        __syncthreads();
        {   // stage B: X-tiles (mt=wv, nt=0..3) += E1(k-chunk hc) @ Ywc
            const int aoff = ((hc * 4 + wv) * 64 + lane) * 8;
            bf16x8 c1h = *(const bf16x8*)&cst[C_C1H + aoff];
            bf16x8 c1l = *(const bf16x8*)&cst[C_C1L + aoff];
            bf16x8 s1h = *(const bf16x8*)&cst[C_S1H + aoff];
            bf16x8 s1l = *(const bf16x8*)&cst[C_S1L + aoff];
            bf16x8 snh = *(const bf16x8*)&cst[C_SNH + aoff];
            bf16x8 snl = *(const bf16x8*)&cst[C_SNL + aoff];
            const int kl = (lane >> 4) * 8;
            #pragma unroll
            for (int nt = 0; nt < 4; ++nt) {
                int nRe = (nt & 1) * 16 + (lane & 15);
                int nIm = 32 + nRe;
                int reIdx = (nRe * 32 + kl) ^ ((nRe & 7) << 3);
                int imIdx = (nIm * 32 + kl) ^ ((nIm & 7) << 3);
                bf16x8 brh = *(const bf16x8*)&yt_hi[reIdx];
                bf16x8 brl = *(const bf16x8*)&yt_lo[reIdx];
                bf16x8 bih = *(const bf16x8*)&yt_hi[imIdx];
                bf16x8 bil = *(const bf16x8*)&yt_lo[imIdx];
                if (nt < 2) {   // X_re = C1@Yr + S1@Yi
                    acc[nt] = MFMA16(c1h, brh, acc[nt]);
                    acc[nt] = MFMA16(c1h, brl, acc[nt]);
                    acc[nt] = MFMA16(c1l, brh, acc[nt]);
                    acc[nt] = MFMA16(s1h, bih, acc[nt]);
                    acc[nt] = MFMA16(s1h, bil, acc[nt]);
                    acc[nt] = MFMA16(s1l, bih, acc[nt]);
                } else {        // X_im = C1@Yi + (-S1)@Yr
                    acc[nt] = MFMA16(c1h, bih, acc[nt]);
                    acc[nt] = MFMA16(c1h, bil, acc[nt]);
                    acc[nt] = MFMA16(c1l, bih, acc[nt]);
                    acc[nt] = MFMA16(snh, brh, acc[nt]);
                    acc[nt] = MFMA16(snh, brl, acc[nt]);
                    acc[nt] = MFMA16(snl, brh, acc[nt]);
                }
            }
        }
        __syncthreads();
    }
    {   // epilogue: X[img][s][n]
        float* Xp = X + (size_t)img * 4096;
        const int sbase = wv * 16 + (lane >> 4) * 4;
        #pragma unroll
        for (int nt = 0; nt < 4; ++nt) {
            int n = nt * 16 + (lane & 15);
            #pragma unroll
            for (int r = 0; r < 4; ++r)
                Xp[(sbase + r) * 64 + n] = acc[nt][r];
        }
    }
}

// ---------------------------------------------------------------------------
// Inverse: per image.
//   G = X*wsum -> GT[n][k] = [[Gr,Gi],[-Gi,Gr]]^T in LDS (split, swizzled)
//   T(256x64) = A1(256x128) @ Gbig    (T cols: [Tr | Ti])
//   out(256x256) = T @ D, 4 row-strips.
// ---------------------------------------------------------------------------
__global__ __launch_bounds__(256)
void inv_kernel(const float* __restrict__ X, const float2* __restrict__ s1,
                const float2* __restrict__ s2, float* __restrict__ out,
                const unsigned short* __restrict__ cst) {
    const int img = blockIdx.x;
    const int c = img & 63;
    const int t = threadIdx.x;
    const int lane = t & 63;
    const int wv = t >> 6;

    __shared__ unsigned short lds[32768];   // 64 KiB
    unsigned short* GTh = lds;              // [64][128]
    unsigned short* GTl = lds + 8192;
    unsigned short* Th  = lds;              // [256][64] (aliases GT after barrier)
    unsigned short* Tl  = lds + 16384;

    {   // phase 0: G = X*wsum -> GT (transposed, duplicated, split)
        const float* Xp = X + (size_t)img * 4096;
        int s = t >> 2;
        int k2b = (t & 3) * 8;
        const float2* wp = (s < 32) ? (s1 + c * 1024 + s * 32 + k2b)
                                    : (s2 + c * 1024 + (s - 32) * 32 + k2b);
        float4 xr0 = *(const float4*)&Xp[s * 64 + k2b];
        float4 xr1 = *(const float4*)&Xp[s * 64 + k2b + 4];
        float4 xi0 = *(const float4*)&Xp[s * 64 + 32 + k2b];
        float4 xi1 = *(const float4*)&Xp[s * 64 + 32 + k2b + 4];
        float xr[8] = {xr0.x,xr0.y,xr0.z,xr0.w,xr1.x,xr1.y,xr1.z,xr1.w};
        float xi[8] = {xi0.x,xi0.y,xi0.z,xi0.w,xi1.x,xi1.y,xi1.z,xi1.w};
        #pragma unroll
        for (int i = 0; i < 8; ++i) {
            int k2 = k2b + i;
            float2 wvv = wp[i];
            float gr = xr[i]*wvv.x - xi[i]*wvv.y;
            float gi = xr[i]*wvv.y + xi[i]*wvv.x;
            unsigned short grh, grl, gih, gil;
            split2(gr, grh, grl); split2(gi, gih, gil);
            int swz = (k2 & 7) << 3;                 // (32+k2)&7 == k2&7
            int i0 = (k2 * 128 + s) ^ swz;           // Gr
            int i1 = ((32 + k2) * 128 + s) ^ swz;    // Gi
            int i2 = (k2 * 128 + 64 + s) ^ swz;      // -Gi
            int i3 = ((32 + k2) * 128 + 64 + s) ^ swz; // Gr
            GTh[i0] = grh; GTl[i0] = grl;
            GTh[i1] = gih; GTl[i1] = gil;
            GTh[i2] = (unsigned short)(gih ^ 0x8000u);
            GTl[i2] = (unsigned short)(gil ^ 0x8000u);
            GTh[i3] = grh; GTl[i3] = grl;
        }
    }
    __syncthreads();

    // phase 1: T = A1 @ Gbig ; wave wv owns mt in [4wv,4wv+4), nt in [0,4)
    f32x4 Tacc[4][4];
    #pragma unroll
    for (int a = 0; a < 4; ++a)
        #pragma unroll
        for (int b = 0; b < 4; ++b) { Tacc[a][b].x=0; Tacc[a][b].y=0; Tacc[a][b].z=0; Tacc[a][b].w=0; }
    {
        const int kb = (lane >> 4) * 8;
        #pragma unroll
        for (int kt = 0; kt < 4; ++kt) {
            bf16x8 bh[4], bl[4];
            #pragma unroll
            for (int nt = 0; nt < 4; ++nt) {
                int n = nt * 16 + (lane & 15);
                int idx = (n * 128 + kt * 32 + kb) ^ ((n & 7) << 3);
                bh[nt] = *(const bf16x8*)&GTh[idx];
                bl[nt] = *(const bf16x8*)&GTl[idx];
            }
            #pragma unroll
            for (int mi = 0; mi < 4; ++mi) {
                int aoff = ((kt * 16 + 4 * wv + mi) * 64 + lane) * 8;
                bf16x8 ah = *(const bf16x8*)&cst[C_A1H + aoff];
                bf16x8 al = *(const bf16x8*)&cst[C_A1L + aoff];
                #pragma unroll
                for (int nt = 0; nt < 4; ++nt) {
                    Tacc[mi][nt] = MFMA16(ah, bh[nt], Tacc[mi][nt]);
                    Tacc[mi][nt] = MFMA16(ah, bl[nt], Tacc[mi][nt]);
                    Tacc[mi][nt] = MFMA16(al, bh[nt], Tacc[mi][nt]);
                }
            }
        }
    }
    __syncthreads();    // all GT reads done before overwriting with T

    {   // write T (split) to LDS [m][k], row-swizzled
        #pragma unroll
        for (int mi = 0; mi < 4; ++mi) {
            int m0 = (4 * wv + mi) * 16 + (lane >> 4) * 4;
            #pragma unroll
            for (int nt = 0; nt < 4; ++nt) {
                int k = nt * 16 + (lane & 15);
                #pragma unroll
                for (int r = 0; r < 4; ++r) {
                    int m = m0 + r;
                    int idx = (m * 64 + k) ^ ((m & 7) << 3);
                    unsigned short hh, ll; split2(Tacc[mi][nt][r], hh, ll);
                    Th[idx] = hh; Tl[idx] = ll;
                }
            }
        }
    }
    __syncthreads();

    // phase 2: out = T @ D, strips of 64 rows; wave wv owns nt in [4wv,4wv+4)
    float* oim = out + (size_t)img * 65536;
    const int kb2 = (lane >> 4) * 8;
    #pragma unroll 1
    for (int strip = 0; strip < 4; ++strip) {
        f32x4 oacc[4][4];
        #pragma unroll
        for (int a = 0; a < 4; ++a)
            #pragma unroll
            for (int b = 0; b < 4; ++b) { oacc[a][b].x=0; oacc[a][b].y=0; oacc[a][b].z=0; oacc[a][b].w=0; }
        #pragma unroll
        for (int kt = 0; kt < 2; ++kt) {
            bf16x8 ah[4], al[4];
            #pragma unroll
            for (int mi = 0; mi < 4; ++mi) {
                int m = (strip * 4 + mi) * 16 + (lane & 15);
                int idx = (m * 64 + kt * 32 + kb2) ^ ((m & 7) << 3);
                ah[mi] = *(const bf16x8*)&Th[idx];
                al[mi] = *(const bf16x8*)&Tl[idx];
            }
            #pragma unroll
            for (int ni = 0; ni < 4; ++ni) {
                int boff = ((kt * 16 + 4 * wv + ni) * 64 + lane) * 8;
                bf16x8 bh = *(const bf16x8*)&cst[C_DH + boff];
                bf16x8 bl = *(const bf16x8*)&cst[C_DL + boff];
                #pragma unroll
                for (int mi = 0; mi < 4; ++mi) {
                    oacc[mi][ni] = MFMA16(ah[mi], bh, oacc[mi][ni]);
                    oacc[mi][ni] = MFMA16(ah[mi], bl, oacc[mi][ni]);
                    oacc[mi][ni] = MFMA16(al[mi], bh, oacc[mi][ni]);
                }
            }
        }
        #pragma unroll
        for (int mi = 0; mi < 4; ++mi) {
            int h = strip * 64 + mi * 16 + (lane >> 4) * 4;
            #pragma unroll
            for (int ni = 0; ni < 4; ++ni) {
                int wc = (4 * wv + ni) * 16 + (lane & 15);
                #pragma unroll
                for (int r = 0; r < 4; ++r)
                    oim[(size_t)(h + r) * 256 + wc] = oacc[mi][ni][r];
            }
        }
    }
}

// ---------------------------------------------------------------------------
extern "C" void kernel_launch(void* const* d_in, const int* in_sizes, int n_in,
                              void* d_out, int out_size, void* d_ws, size_t ws_size,
                              hipStream_t stream) {
    const float* x   = (const float*)d_in[0];
    const float* w1r = (const float*)d_in[1];
    const float* w1i = (const float*)d_in[2];
    const float* w2r = (const float*)d_in[3];
    const float* w2i = (const float*)d_in[4];
    float* out = (float*)d_out;

    char* ws = (char*)d_ws;
    float* X   = (float*)ws;                                // 16 MiB  (1024*64*64 f32)
    float2* s1 = (float2*)(ws + 16777216);                  // 512 KiB
    float2* s2 = (float2*)(ws + 16777216 + 524288);         // 512 KiB
    unsigned short* cst = (unsigned short*)(ws + 17825792); // 448 KiB prefrag consts

    hipLaunchKernelGGL(const_kernel, dim3(448), dim3(256), 0, stream, cst);
    hipLaunchKernelGGL(wsum_kernel, dim3(256), dim3(256), 0, stream,
                       w1r, w1i, w2r, w2i, s1, s2);
    hipLaunchKernelGGL(fwd_kernel, dim3(1024), dim3(256), 0, stream, x, X, cst);
    hipLaunchKernelGGL(inv_kernel, dim3(1024), dim3(256), 0, stream, X, s1, s2, out, cst);
}

// Round 2
// 552.521 us; speedup vs baseline: 1.8533x; 1.0036x over previous
//
#include <hip/hip_runtime.h>
#include <math.h>

#define TWO_PI 6.28318530717958647692f

typedef __attribute__((ext_vector_type(8))) short bf16x8;
typedef __attribute__((ext_vector_type(4))) float f32x4;
typedef __attribute__((ext_vector_type(4))) short short4v;

#define MFMA16(A,B,C) __builtin_amdgcn_mfma_f32_16x16x32_bf16((A),(B),(C),0,0,0)

// Problem: B=16, C=64, H=W=256, M1=M2=32. Kept rows f = s<32 ? s : s+192, cols k2<32.
// Pipeline (all matmuls on MFMA, hi/lo-split bf16, fp32 accum):
//   fwd : Yw = x @ B2 (w-DFT), X = E1c @ Yw (h-DFT)           -> X[img][64][64] (Re|Im)
//   inv : G = X*wsum ; T = [C|S] @ [[Gr,Gi],[-Gi,Gr]] ; out = [Tr|Ti] @ D
// Constants are PRE-FRAGMENTED in MFMA lane order (16B load per fragment).

// const region offsets in shorts (hi then lo per matrix)
#define C_B2H 0          // B-op 256x64   (8 kt x 4 nt)
#define C_B2L 16384
#define C_C1H 32768      // A-op 64x256   (4 mt x 8 kt)  cos(f h)
#define C_C1L 49152
#define C_S1H 65536      //               sin(f h)
#define C_S1L 81920
#define C_SNH 98304      //              -sin(f h)
#define C_SNL 114688
#define C_A1H 131072     // A-op 256x128  (16 mt x 4 kt) [C | S]
#define C_A1L 163840
#define C_DH  196608     // B-op 64x256   (2 kt x 16 nt) [a cos ; -a sin]
#define C_DL  212992

__device__ __forceinline__ unsigned short bhi(float v) {
    union { float f; unsigned u; } x; x.f = v;
    return (unsigned short)(x.u >> 16);
}
__device__ __forceinline__ float bval(unsigned short h) {
    union { unsigned u; float f; } x; x.u = ((unsigned)h) << 16;
    return x.f;
}
__device__ __forceinline__ void split2(float v, unsigned short& hi, unsigned short& lo) {
    hi = bhi(v);
    lo = bhi(v - bval(hi));
}

// ---------------------------------------------------------------------------
// Setup: twiddle matrices, pre-fragmented + hi/lo split. 114688 value slots.
// ---------------------------------------------------------------------------
__global__ __launch_bounds__(256)
void const_kernel(unsigned short* __restrict__ cst) {
    int e = blockIdx.x * 256 + threadIdx.x;
    const float w0 = TWO_PI / 256.0f;
    float v; int i, baseH, baseL;
    if (e < 16384) {                        // B2: [cos(k2 w) | -sin(k2 w)]
        i = e; baseH = C_B2H; baseL = C_B2L;
        int j = i & 7, lane = (i >> 3) & 63, tt = i >> 9;
        int nt = tt & 3, kt = tt >> 2;
        int k = kt * 32 + (lane >> 4) * 8 + j;       // w
        int n = nt * 16 + (lane & 15);
        int fr = n & 31;
        float s_, c_;
        sincosf(w0 * (float)((fr * k) & 255), &s_, &c_);
        v = (n < 32) ? c_ : -s_;
    } else if (e < 65536) {                 // C1 / S1 / -S1 over (s,h)
        int mid = (e - 16384) >> 14;
        i = (e - 16384) & 16383;
        baseH = C_C1H + mid * 32768; baseL = baseH + 16384;
        int j = i & 7, lane = (i >> 3) & 63, tt = i >> 9;
        int mt = tt & 3, kt = tt >> 2;
        int s = mt * 16 + (lane & 15);
        int h = kt * 32 + (lane >> 4) * 8 + j;
        int f = (s < 32) ? s : s + 192;
        float s_, c_;
        sincosf(w0 * (float)((f * h) & 255), &s_, &c_);
        v = (mid == 0) ? c_ : ((mid == 1) ? s_ : -s_);
    } else if (e < 98304) {                 // A1: [C(h,s) | S(h,s)]
        i = e - 65536; baseH = C_A1H; baseL = C_A1L;
        int j = i & 7, lane = (i >> 3) & 63, tt = i >> 9;
        int mt = tt & 15, kt = tt >> 4;
        int h = mt * 16 + (lane & 15);
        int k = kt * 32 + (lane >> 4) * 8 + j;
        int s = k & 63;
        int f = (s < 32) ? s : s + 192;
        float s_, c_;
        sincosf(w0 * (float)((f * h) & 255), &s_, &c_);
        v = (k < 64) ? c_ : s_;
    } else {                                // D: [a cos(k2 w) ; -a sin(k2 w)], a = 1 if k2==0 else 2
        i = e - 98304; baseH = C_DH; baseL = C_DL;
        int j = i & 7, lane = (i >> 3) & 63, tt = i >> 9;
        int nt = tt & 15, kt = tt >> 4;
        int wc = nt * 16 + (lane & 15);
        int k = kt * 32 + (lane >> 4) * 8 + j;
        int k2 = k & 31;
        float a = (k2 == 0) ? 1.f : 2.f;
        float s_, c_;
        sincosf(w0 * (float)((k2 * wc) & 255), &s_, &c_);
        v = (k < 32) ? a * c_ : -a * s_;
    }
    unsigned short hi, lo; split2(v, hi, lo);
    cst[baseH + i] = hi;
    cst[baseL + i] = lo;
}

// ---------------------------------------------------------------------------
// wsum two-stage: stage 1 sums 8 j's per block (512 blocks, float4 loads),
// partials parked in the X workspace region (X is written later in-stream).
// part layout: [arr 0..3][jp 0..7][e4 0..16383] float4
// ---------------------------------------------------------------------------
__global__ __launch_bounds__(256)
void wsum_part(const float* __restrict__ w1r, const float* __restrict__ w1i,
               const float* __restrict__ w2r, const float* __restrict__ w2i,
               float4* __restrict__ part) {
    const int jp = blockIdx.x >> 6;                       // 0..7
    const int e4 = (blockIdx.x & 63) * 256 + threadIdx.x; // 0..16383
    const float4* A = (const float4*)w1r;
    const float4* Bv = (const float4*)w1i;
    const float4* Cv = (const float4*)w2r;
    const float4* Dv = (const float4*)w2i;
    float4 a = make_float4(0.f,0.f,0.f,0.f), b = a, c = a, d = a;
    #pragma unroll
    for (int jj = 0; jj < 8; ++jj) {
        int idx = (jp * 8 + jj) * 16384 + e4;
        float4 v;
        v = A[idx];  a.x += v.x; a.y += v.y; a.z += v.z; a.w += v.w;
        v = Bv[idx]; b.x += v.x; b.y += v.y; b.z += v.z; b.w += v.w;
        v = Cv[idx]; c.x += v.x; c.y += v.y; c.z += v.z; c.w += v.w;
        v = Dv[idx]; d.x += v.x; d.y += v.y; d.z += v.z; d.w += v.w;
    }
    part[(0 * 8 + jp) * 16384 + e4] = a;
    part[(1 * 8 + jp) * 16384 + e4] = b;
    part[(2 * 8 + jp) * 16384 + e4] = c;
    part[(3 * 8 + jp) * 16384 + e4] = d;
}

__global__ __launch_bounds__(256)
void wsum_reduce(const float4* __restrict__ part,
                 float4* __restrict__ s1, float4* __restrict__ s2) {
    const int e4 = blockIdx.x * 256 + threadIdx.x;        // 0..16383
    float4 a = make_float4(0.f,0.f,0.f,0.f), b = a, c = a, d = a;
    #pragma unroll
    for (int jp = 0; jp < 8; ++jp) {
        float4 v;
        v = part[(0 * 8 + jp) * 16384 + e4]; a.x += v.x; a.y += v.y; a.z += v.z; a.w += v.w;
        v = part[(1 * 8 + jp) * 16384 + e4]; b.x += v.x; b.y += v.y; b.z += v.z; b.w += v.w;
        v = part[(2 * 8 + jp) * 16384 + e4]; c.x += v.x; c.y += v.y; c.z += v.z; c.w += v.w;
        v = part[(3 * 8 + jp) * 16384 + e4]; d.x += v.x; d.y += v.y; d.z += v.z; d.w += v.w;
    }
    const float sc = 1.0f / 65536.0f;
    // s1/s2 are float2[e]=(re,im); as float4: {re,im,re,im}
    s1[e4 * 2]     = make_float4(a.x * sc, b.x * sc, a.y * sc, b.y * sc);
    s1[e4 * 2 + 1] = make_float4(a.z * sc, b.z * sc, a.w * sc, b.w * sc);
    s2[e4 * 2]     = make_float4(c.x * sc, d.x * sc, c.y * sc, d.y * sc);
    s2[e4 * 2 + 1] = make_float4(c.z * sc, d.z * sc, c.w * sc, d.w * sc);
}

// ---------------------------------------------------------------------------
// Forward: per image. X[s][n] (n<32 Re, n>=32 Im), fp32.
//   chunk 32 h-rows (register-prefetched): xc -> LDS split; Ywc = xc @ B2;
//   Ywc -> YT (transposed, split); X += C1@Yr + S1@Yi / C1@Yi - S1@Yr.
// ---------------------------------------------------------------------------
__global__ __launch_bounds__(256)
void fwd_kernel(const float* __restrict__ x, float* __restrict__ X,
                const unsigned short* __restrict__ cst) {
    const int img = blockIdx.x;
    const int t = threadIdx.x;
    const int lane = t & 63;
    const int wv = t >> 6;

    __shared__ unsigned short xs_hi[8192], xs_lo[8192];  // [32][256] swizzled
    __shared__ unsigned short yt_hi[2048], yt_lo[2048];  // [64][32]  swizzled

    f32x4 acc[4];
    #pragma unroll
    for (int i = 0; i < 4; ++i) { acc[i].x = 0; acc[i].y = 0; acc[i].z = 0; acc[i].w = 0; }

    const int mt2  = wv >> 1;          // stage-A tile row (both tiles share it)
    const int nt2b = (wv & 1) * 2;     // stage-A tile col base

    const float* xim = x + (size_t)img * 65536;
    const int r_st  = t >> 3;
    const int c4_st = t & 7;
    const float4* src = (const float4*)xim + r_st * 64 + c4_st;

    // prefetch chunk 0 into registers
    float4 pre[8];
    #pragma unroll
    for (int i = 0; i < 8; ++i) pre[i] = src[i * 8];

    #pragma unroll 1
    for (int hc = 0; hc < 8; ++hc) {
        {   // registers -> LDS (split bf16, row-swizzle)
            #pragma unroll
            for (int i = 0; i < 8; ++i) {
                float4 vx = pre[i];
                int cc = (c4_st + i * 8) * 4;
                int idx = (r_st * 256 + cc) ^ ((r_st & 7) << 3);
                unsigned short h0,l0,h1,l1,h2,l2,h3,l3;
                split2(vx.x, h0, l0); split2(vx.y, h1, l1);
                split2(vx.z, h2, l2); split2(vx.w, h3, l3);
                short4v vh, vl;
                vh.x=(short)h0; vh.y=(short)h1; vh.z=(short)h2; vh.w=(short)h3;
                vl.x=(short)l0; vl.y=(short)l1; vl.z=(short)l2; vl.w=(short)l3;
                *(short4v*)&xs_hi[idx] = vh;
                *(short4v*)&xs_lo[idx] = vl;
            }
        }
        __syncthreads();
        if (hc < 7) {   // issue next chunk's loads; latency hides under MFMAs
            const float4* nsrc = src + (hc + 1) * 2048;
            #pragma unroll
            for (int i = 0; i < 8; ++i) pre[i] = nsrc[i * 8];
        }
        // stage A: Ywc(32x64) = xc @ B2, 2 tiles/wave
        f32x4 acc2[2];
        acc2[0].x=0; acc2[0].y=0; acc2[0].z=0; acc2[0].w=0;
        acc2[1].x=0; acc2[1].y=0; acc2[1].z=0; acc2[1].w=0;
        {
            const int mrow = mt2 * 16 + (lane & 15);
            const int kb = (lane >> 4) * 8;
            #pragma unroll
            for (int kt = 0; kt < 8; ++kt) {
                int aidx = (mrow * 256 + kt * 32 + kb) ^ ((mrow & 7) << 3);
                bf16x8 ah = *(const bf16x8*)&xs_hi[aidx];
                bf16x8 al = *(const bf16x8*)&xs_lo[aidx];
                #pragma unroll
                for (int q = 0; q < 2; ++q) {
                    int boff = ((kt * 4 + nt2b + q) * 64 + lane) * 8;
                    bf16x8 bh = *(const bf16x8*)&cst[C_B2H + boff];
                    bf16x8 bl = *(const bf16x8*)&cst[C_B2L + boff];
                    acc2[q] = MFMA16(ah, bh, acc2[q]);
                    acc2[q] = MFMA16(ah, bl, acc2[q]);
                    acc2[q] = MFMA16(al, bh, acc2[q]);
                }
            }
        }
        {   // Ywc -> YT[n][h'] (transposed, split); pack 4 rows per b64 write
            const int hbase = mt2 * 16 + (lane >> 4) * 4;
            #pragma unroll
            for (int q = 0; q < 2; ++q) {
                int n = (nt2b + q) * 16 + (lane & 15);
                int idx = (n * 32 + hbase) ^ ((n & 7) << 3);
                short4v vh, vl; unsigned short hh, ll;
                split2(acc2[q][0], hh, ll); vh.x=(short)hh; vl.x=(short)ll;
                split2(acc2[q][1], hh, ll); vh.y=(short)hh; vl.y=(short)ll;
                split2(acc2[q][2], hh, ll); vh.z=(short)hh; vl.z=(short)ll;
                split2(acc2[q][3], hh, ll); vh.w=(short)hh; vl.w=(short)ll;
                *(short4v*)&yt_hi[idx] = vh;
                *(short4v*)&yt_lo[idx] = vl;
            }
        }
        __syncthreads();
        {   // stage B: X-tiles (mt=wv, nt=0..3) += E1(k-chunk hc) @ Ywc
            const int aoff = ((hc * 4 + wv) * 64 + lane) * 8;
            bf16x8 c1h = *(const bf16x8*)&cst[C_C1H + aoff];
            bf16x8 c1l = *(const bf16x8*)&cst[C_C1L + aoff];
            bf16x8 s1h = *(const bf16x8*)&cst[C_S1H + aoff];
            bf16x8 s1l = *(const bf16x8*)&cst[C_S1L + aoff];
            bf16x8 snh = *(const bf16x8*)&cst[C_SNH + aoff];
            bf16x8 snl = *(const bf16x8*)&cst[C_SNL + aoff];
            const int kl = (lane >> 4) * 8;
            #pragma unroll
            for (int nt = 0; nt < 4; ++nt) {
                int nRe = (nt & 1) * 16 + (lane & 15);
                int nIm = 32 + nRe;
                int reIdx = (nRe * 32 + kl) ^ ((nRe & 7) << 3);
                int imIdx = (nIm * 32 + kl) ^ ((nIm & 7) << 3);
                bf16x8 brh = *(const bf16x8*)&yt_hi[reIdx];
                bf16x8 brl = *(const bf16x8*)&yt_lo[reIdx];
                bf16x8 bih = *(const bf16x8*)&yt_hi[imIdx];
                bf16x8 bil = *(const bf16x8*)&yt_lo[imIdx];
                if (nt < 2) {   // X_re = C1@Yr + S1@Yi
                    acc[nt] = MFMA16(c1h, brh, acc[nt]);
                    acc[nt] = MFMA16(c1h, brl, acc[nt]);
                    acc[nt] = MFMA16(c1l, brh, acc[nt]);
                    acc[nt] = MFMA16(s1h, bih, acc[nt]);
                    acc[nt] = MFMA16(s1h, bil, acc[nt]);
                    acc[nt] = MFMA16(s1l, bih, acc[nt]);
                } else {        // X_im = C1@Yi + (-S1)@Yr
                    acc[nt] = MFMA16(c1h, bih, acc[nt]);
                    acc[nt] = MFMA16(c1h, bil, acc[nt]);
                    acc[nt] = MFMA16(c1l, bih, acc[nt]);
                    acc[nt] = MFMA16(snh, brh, acc[nt]);
                    acc[nt] = MFMA16(snh, brl, acc[nt]);
                    acc[nt] = MFMA16(snl, brh, acc[nt]);
                }
            }
        }
        __syncthreads();
    }
    {   // epilogue: X[img][s][n]
        float* Xp = X + (size_t)img * 4096;
        const int sbase = wv * 16 + (lane >> 4) * 4;
        #pragma unroll
        for (int nt = 0; nt < 4; ++nt) {
            int n = nt * 16 + (lane & 15);
            #pragma unroll
            for (int r = 0; r < 4; ++r)
                Xp[(sbase + r) * 64 + n] = acc[nt][r];
        }
    }
}

// ---------------------------------------------------------------------------
// Inverse: per image.
//   G = X*wsum -> GT[n][k] = [[Gr,Gi],[-Gi,Gr]]^T in LDS (split, swizzled)
//   T(256x64) = A1(256x128) @ Gbig    (T cols: [Tr | Ti])
//   out(256x256) = T @ D, 4 row-strips.
// ---------------------------------------------------------------------------
__global__ __launch_bounds__(256)
void inv_kernel(const float* __restrict__ X, const float2* __restrict__ s1,
                const float2* __restrict__ s2, float* __restrict__ out,
                const unsigned short* __restrict__ cst) {
    const int img = blockIdx.x;
    const int c = img & 63;
    const int t = threadIdx.x;
    const int lane = t & 63;
    const int wv = t >> 6;

    __shared__ unsigned short lds[32768];   // 64 KiB
    unsigned short* GTh = lds;              // [64][128]
    unsigned short* GTl = lds + 8192;
    unsigned short* Th  = lds;              // [256][64] (aliases GT after barrier)
    unsigned short* Tl  = lds + 16384;

    {   // phase 0: G = X*wsum -> GT (transposed, duplicated, split)
        const float* Xp = X + (size_t)img * 4096;
        int s = t >> 2;
        int k2b = (t & 3) * 8;
        const float2* wp = (s < 32) ? (s1 + c * 1024 + s * 32 + k2b)
                                    : (s2 + c * 1024 + (s - 32) * 32 + k2b);
        float4 xr0 = *(const float4*)&Xp[s * 64 + k2b];
        float4 xr1 = *(const float4*)&Xp[s * 64 + k2b + 4];
        float4 xi0 = *(const float4*)&Xp[s * 64 + 32 + k2b];
        float4 xi1 = *(const float4*)&Xp[s * 64 + 32 + k2b + 4];
        float xr[8] = {xr0.x,xr0.y,xr0.z,xr0.w,xr1.x,xr1.y,xr1.z,xr1.w};
        float xi[8] = {xi0.x,xi0.y,xi0.z,xi0.w,xi1.x,xi1.y,xi1.z,xi1.w};
        #pragma unroll
        for (int i = 0; i < 8; ++i) {
            int k2 = k2b + i;
            float2 wvv = wp[i];
            float gr = xr[i]*wvv.x - xi[i]*wvv.y;
            float gi = xr[i]*wvv.y + xi[i]*wvv.x;
            unsigned short grh, grl, gih, gil;
            split2(gr, grh, grl); split2(gi, gih, gil);
            int swz = (k2 & 7) << 3;                 // (32+k2)&7 == k2&7
            int i0 = (k2 * 128 + s) ^ swz;           // Gr
            int i1 = ((32 + k2) * 128 + s) ^ swz;    // Gi
            int i2 = (k2 * 128 + 64 + s) ^ swz;      // -Gi
            int i3 = ((32 + k2) * 128 + 64 + s) ^ swz; // Gr
            GTh[i0] = grh; GTl[i0] = grl;
            GTh[i1] = gih; GTl[i1] = gil;
            GTh[i2] = (unsigned short)(gih ^ 0x8000u);
            GTl[i2] = (unsigned short)(gil ^ 0x8000u);
            GTh[i3] = grh; GTl[i3] = grl;
        }
    }
    __syncthreads();

    // phase 1: T = A1 @ Gbig ; wave wv owns mt in [4wv,4wv+4), nt in [0,4)
    f32x4 Tacc[4][4];
    #pragma unroll
    for (int a = 0; a < 4; ++a)
        #pragma unroll
        for (int b = 0; b < 4; ++b) { Tacc[a][b].x=0; Tacc[a][b].y=0; Tacc[a][b].z=0; Tacc[a][b].w=0; }
    {
        const int kb = (lane >> 4) * 8;
        #pragma unroll
        for (int kt = 0; kt < 4; ++kt) {
            bf16x8 bh[4], bl[4];
            #pragma unroll
            for (int nt = 0; nt < 4; ++nt) {
                int n = nt * 16 + (lane & 15);
                int idx = (n * 128 + kt * 32 + kb) ^ ((n & 7) << 3);
                bh[nt] = *(const bf16x8*)&GTh[idx];
                bl[nt] = *(const bf16x8*)&GTl[idx];
            }
            #pragma unroll
            for (int mi = 0; mi < 4; ++mi) {
                int aoff = ((kt * 16 + 4 * wv + mi) * 64 + lane) * 8;
                bf16x8 ah = *(const bf16x8*)&cst[C_A1H + aoff];
                bf16x8 al = *(const bf16x8*)&cst[C_A1L + aoff];
                #pragma unroll
                for (int nt = 0; nt < 4; ++nt) {
                    Tacc[mi][nt] = MFMA16(ah, bh[nt], Tacc[mi][nt]);
                    Tacc[mi][nt] = MFMA16(ah, bl[nt], Tacc[mi][nt]);
                    Tacc[mi][nt] = MFMA16(al, bh[nt], Tacc[mi][nt]);
                }
            }
        }
    }
    __syncthreads();    // all GT reads done before overwriting with T

    {   // write T (split) to LDS [m][k], row-swizzled
        #pragma unroll
        for (int mi = 0; mi < 4; ++mi) {
            int m0 = (4 * wv + mi) * 16 + (lane >> 4) * 4;
            #pragma unroll
            for (int nt = 0; nt < 4; ++nt) {
                int k = nt * 16 + (lane & 15);
                #pragma unroll
                for (int r = 0; r < 4; ++r) {
                    int m = m0 + r;
                    int idx = (m * 64 + k) ^ ((m & 7) << 3);
                    unsigned short hh, ll; split2(Tacc[mi][nt][r], hh, ll);
                    Th[idx] = hh; Tl[idx] = ll;
                }
            }
        }
    }
    __syncthreads();

    // phase 2: out = T @ D, strips of 64 rows; wave wv owns nt in [4wv,4wv+4)
    float* oim = out + (size_t)img * 65536;
    const int kb2 = (lane >> 4) * 8;
    #pragma unroll 1
    for (int strip = 0; strip < 4; ++strip) {
        f32x4 oacc[4][4];
        #pragma unroll
        for (int a = 0; a < 4; ++a)
            #pragma unroll
            for (int b = 0; b < 4; ++b) { oacc[a][b].x=0; oacc[a][b].y=0; oacc[a][b].z=0; oacc[a][b].w=0; }
        #pragma unroll
        for (int kt = 0; kt < 2; ++kt) {
            bf16x8 ah[4], al[4];
            #pragma unroll
            for (int mi = 0; mi < 4; ++mi) {
                int m = (strip * 4 + mi) * 16 + (lane & 15);
                int idx = (m * 64 + kt * 32 + kb2) ^ ((m & 7) << 3);
                ah[mi] = *(const bf16x8*)&Th[idx];
                al[mi] = *(const bf16x8*)&Tl[idx];
            }
            #pragma unroll
            for (int ni = 0; ni < 4; ++ni) {
                int boff = ((kt * 16 + 4 * wv + ni) * 64 + lane) * 8;
                bf16x8 bh = *(const bf16x8*)&cst[C_DH + boff];
                bf16x8 bl = *(const bf16x8*)&cst[C_DL + boff];
                #pragma unroll
                for (int mi = 0; mi < 4; ++mi) {
                    oacc[mi][ni] = MFMA16(ah[mi], bh, oacc[mi][ni]);
                    oacc[mi][ni] = MFMA16(ah[mi], bl, oacc[mi][ni]);
                    oacc[mi][ni] = MFMA16(al[mi], bh, oacc[mi][ni]);
                }
            }
        }
        #pragma unroll
        for (int mi = 0; mi < 4; ++mi) {
            int h = strip * 64 + mi * 16 + (lane >> 4) * 4;
            #pragma unroll
            for (int ni = 0; ni < 4; ++ni) {
                int wc = (4 * wv + ni) * 16 + (lane & 15);
                #pragma unroll
                for (int r = 0; r < 4; ++r)
                    oim[(size_t)(h + r) * 256 + wc] = oacc[mi][ni][r];
            }
        }
    }
}

// ---------------------------------------------------------------------------
extern "C" void kernel_launch(void* const* d_in, const int* in_sizes, int n_in,
                              void* d_out, int out_size, void* d_ws, size_t ws_size,
                              hipStream_t stream) {
    const float* x   = (const float*)d_in[0];
    const float* w1r = (const float*)d_in[1];
    const float* w1i = (const float*)d_in[2];
    const float* w2r = (const float*)d_in[3];
    const float* w2i = (const float*)d_in[4];
    float* out = (float*)d_out;

    char* ws = (char*)d_ws;
    float* X   = (float*)ws;                                // 16 MiB  (1024*64*64 f32)
    float2* s1 = (float2*)(ws + 16777216);                  // 512 KiB
    float2* s2 = (float2*)(ws + 16777216 + 524288);         // 512 KiB
    unsigned short* cst = (unsigned short*)(ws + 17825792); // 448 KiB prefrag consts
    float4* part = (float4*)ws;                             // aliases X: dead before fwd

    hipLaunchKernelGGL(const_kernel, dim3(448), dim3(256), 0, stream, cst);
    hipLaunchKernelGGL(wsum_part, dim3(512), dim3(256), 0, stream,
                       w1r, w1i, w2r, w2i, part);
    hipLaunchKernelGGL(wsum_reduce, dim3(64), dim3(256), 0, stream,
                       part, (float4*)s1, (float4*)s2);
    hipLaunchKernelGGL(fwd_kernel, dim3(1024), dim3(256), 0, stream, x, X, cst);
    hipLaunchKernelGGL(inv_kernel, dim3(1024), dim3(256), 0, stream, X, s1, s2, out, cst);
}

// Round 4
// 544.728 us; speedup vs baseline: 1.8798x; 1.0143x over previous
//
#include <hip/hip_runtime.h>
#include <math.h>

#define TWO_PI 6.28318530717958647692f

typedef __attribute__((ext_vector_type(8))) short bf16x8;
typedef __attribute__((ext_vector_type(4))) float f32x4;
typedef __attribute__((ext_vector_type(4))) short short4v;

#define MFMA16(A,B,C) __builtin_amdgcn_mfma_f32_16x16x32_bf16((A),(B),(C),0,0,0)

// Problem: B=16, C=64, H=W=256, M1=M2=32. Kept rows f = s<32 ? s : s+192, cols k2<32.
// Fused pipeline per image (all matmuls MFMA, hi/lo-split bf16, fp32 accum):
//   Yw = x @ B2 (w-DFT); X = E1c @ Yw (h-DFT)  [X stays in registers]
//   G = X*wsum -> GT in LDS ; T = [C|S] @ [[Gr,Gi],[-Gi,Gr]] ; out = [Tr|Ti] @ D

// const region offsets in shorts (hi then lo per matrix)
#define C_B2H 0          // B-op 256x64   (8 kt x 4 nt)
#define C_B2L 16384
#define C_C1H 32768      // A-op 64x256   (4 mt x 8 kt)  cos(f h)
#define C_C1L 49152
#define C_S1H 65536      //               sin(f h)
#define C_S1L 81920
#define C_SNH 98304      //              -sin(f h)
#define C_SNL 114688
#define C_A1H 131072     // A-op 256x128  (16 mt x 4 kt) [C | S]
#define C_A1L 163840
#define C_DH  196608     // B-op 64x256   (2 kt x 16 nt) [a cos ; -a sin]
#define C_DL  212992

__device__ __forceinline__ unsigned short bhi(float v) {
    union { float f; unsigned u; } x; x.f = v;
    return (unsigned short)(x.u >> 16);
}
__device__ __forceinline__ float bval(unsigned short h) {
    union { unsigned u; float f; } x; x.u = ((unsigned)h) << 16;
    return x.f;
}
__device__ __forceinline__ void split2(float v, unsigned short& hi, unsigned short& lo) {
    hi = bhi(v);
    lo = bhi(v - bval(hi));
}

// ---------------------------------------------------------------------------
// Setup: twiddle matrices, pre-fragmented + hi/lo split. 114688 value slots.
// ---------------------------------------------------------------------------
__global__ __launch_bounds__(256)
void const_kernel(unsigned short* __restrict__ cst) {
    int e = blockIdx.x * 256 + threadIdx.x;
    const float w0 = TWO_PI / 256.0f;
    float v; int i, baseH, baseL;
    if (e < 16384) {                        // B2: [cos(k2 w) | -sin(k2 w)]
        i = e; baseH = C_B2H; baseL = C_B2L;
        int j = i & 7, lane = (i >> 3) & 63, tt = i >> 9;
        int nt = tt & 3, kt = tt >> 2;
        int k = kt * 32 + (lane >> 4) * 8 + j;       // w
        int n = nt * 16 + (lane & 15);
        int fr = n & 31;
        float s_, c_;
        sincosf(w0 * (float)((fr * k) & 255), &s_, &c_);
        v = (n < 32) ? c_ : -s_;
    } else if (e < 65536) {                 // C1 / S1 / -S1 over (s,h)
        int mid = (e - 16384) >> 14;
        i = (e - 16384) & 16383;
        baseH = C_C1H + mid * 32768; baseL = baseH + 16384;
        int j = i & 7, lane = (i >> 3) & 63, tt = i >> 9;
        int mt = tt & 3, kt = tt >> 2;
        int s = mt * 16 + (lane & 15);
        int h = kt * 32 + (lane >> 4) * 8 + j;
        int f = (s < 32) ? s : s + 192;
        float s_, c_;
        sincosf(w0 * (float)((f * h) & 255), &s_, &c_);
        v = (mid == 0) ? c_ : ((mid == 1) ? s_ : -s_);
    } else if (e < 98304) {                 // A1: [C(h,s) | S(h,s)]
        i = e - 65536; baseH = C_A1H; baseL = C_A1L;
        int j = i & 7, lane = (i >> 3) & 63, tt = i >> 9;
        int mt = tt & 15, kt = tt >> 4;
        int h = mt * 16 + (lane & 15);
        int k = kt * 32 + (lane >> 4) * 8 + j;
        int s = k & 63;
        int f = (s < 32) ? s : s + 192;
        float s_, c_;
        sincosf(w0 * (float)((f * h) & 255), &s_, &c_);
        v = (k < 64) ? c_ : s_;
    } else {                                // D: [a cos(k2 w) ; -a sin(k2 w)], a = 1 if k2==0 else 2
        i = e - 98304; baseH = C_DH; baseL = C_DL;
        int j = i & 7, lane = (i >> 3) & 63, tt = i >> 9;
        int nt = tt & 15, kt = tt >> 4;
        int wc = nt * 16 + (lane & 15);
        int k = kt * 32 + (lane >> 4) * 8 + j;
        int k2 = k & 31;
        float a = (k2 == 0) ? 1.f : 2.f;
        float s_, c_;
        sincosf(w0 * (float)((k2 * wc) & 255), &s_, &c_);
        v = (k < 32) ? a * c_ : -a * s_;
    }
    unsigned short hi, lo; split2(v, hi, lo);
    cst[baseH + i] = hi;
    cst[baseL + i] = lo;
}

// ---------------------------------------------------------------------------
// wsum two-stage: stage 1 sums 8 j's per block (512 blocks, float4 loads),
// partials parked in workspace (dead before fused kernel runs).
// part layout: [arr 0..3][jp 0..7][e4 0..16383] float4
// ---------------------------------------------------------------------------
__global__ __launch_bounds__(256)
void wsum_part(const float* __restrict__ w1r, const float* __restrict__ w1i,
               const float* __restrict__ w2r, const float* __restrict__ w2i,
               float4* __restrict__ part) {
    const int jp = blockIdx.x >> 6;                       // 0..7
    const int e4 = (blockIdx.x & 63) * 256 + threadIdx.x; // 0..16383
    const float4* A = (const float4*)w1r;
    const float4* Bv = (const float4*)w1i;
    const float4* Cv = (const float4*)w2r;
    const float4* Dv = (const float4*)w2i;
    float4 a = make_float4(0.f,0.f,0.f,0.f), b = a, c = a, d = a;
    #pragma unroll
    for (int jj = 0; jj < 8; ++jj) {
        int idx = (jp * 8 + jj) * 16384 + e4;
        float4 v;
        v = A[idx];  a.x += v.x; a.y += v.y; a.z += v.z; a.w += v.w;
        v = Bv[idx]; b.x += v.x; b.y += v.y; b.z += v.z; b.w += v.w;
        v = Cv[idx]; c.x += v.x; c.y += v.y; c.z += v.z; c.w += v.w;
        v = Dv[idx]; d.x += v.x; d.y += v.y; d.z += v.z; d.w += v.w;
    }
    part[(0 * 8 + jp) * 16384 + e4] = a;
    part[(1 * 8 + jp) * 16384 + e4] = b;
    part[(2 * 8 + jp) * 16384 + e4] = c;
    part[(3 * 8 + jp) * 16384 + e4] = d;
}

__global__ __launch_bounds__(256)
void wsum_reduce(const float4* __restrict__ part,
                 float4* __restrict__ s1, float4* __restrict__ s2) {
    const int e4 = blockIdx.x * 256 + threadIdx.x;        // 0..16383
    float4 a = make_float4(0.f,0.f,0.f,0.f), b = a, c = a, d = a;
    #pragma unroll
    for (int jp = 0; jp < 8; ++jp) {
        float4 v;
        v = part[(0 * 8 + jp) * 16384 + e4]; a.x += v.x; a.y += v.y; a.z += v.z; a.w += v.w;
        v = part[(1 * 8 + jp) * 16384 + e4]; b.x += v.x; b.y += v.y; b.z += v.z; b.w += v.w;
        v = part[(2 * 8 + jp) * 16384 + e4]; c.x += v.x; c.y += v.y; c.z += v.z; c.w += v.w;
        v = part[(3 * 8 + jp) * 16384 + e4]; d.x += v.x; d.y += v.y; d.z += v.z; d.w += v.w;
    }
    const float sc = 1.0f / 65536.0f;
    // s1/s2 are float2[e]=(re,im); as float4: {re,im,re,im}
    s1[e4 * 2]     = make_float4(a.x * sc, b.x * sc, a.y * sc, b.y * sc);
    s1[e4 * 2 + 1] = make_float4(a.z * sc, b.z * sc, a.w * sc, b.w * sc);
    s2[e4 * 2]     = make_float4(c.x * sc, d.x * sc, c.y * sc, d.y * sc);
    s2[e4 * 2 + 1] = make_float4(c.z * sc, d.z * sc, c.w * sc, d.w * sc);
}

// ---------------------------------------------------------------------------
// Fused forward+inverse, one block per (b,c) image.
// LDS overlay: xs(32K) -> GT(32K) -> T(64K); yt separate 8K.
// ---------------------------------------------------------------------------
__global__ __launch_bounds__(256)
void fused_kernel(const float* __restrict__ x,
                  const float2* __restrict__ s1, const float2* __restrict__ s2,
                  float* __restrict__ out, const unsigned short* __restrict__ cst) {
    const int img = blockIdx.x;
    const int c = img & 63;
    const int t = threadIdx.x;
    const int lane = t & 63;
    const int wv = t >> 6;

    __shared__ unsigned short lds[32768];                // 64 KiB overlay
    __shared__ unsigned short yt_hi[2048], yt_lo[2048];  // [64][32] swizzled
    unsigned short* xs_hi = lds;                         // [32][256] swizzled
    unsigned short* xs_lo = lds + 8192;

    // wsum early loads (L2-resident; 16 images share each c-slice)
    // thread covers s = wv*16 + (lane>>4)*4 + r, k2 = j*16 + (lane&15)
    float2 wreg[2][4];
    {
        const float2* wbase = ((wv < 2) ? s1 : s2) + c * 1024
                              + ((wv & 1) * 16 + (lane >> 4) * 4) * 32;
        #pragma unroll
        for (int r = 0; r < 4; ++r) {
            wreg[0][r] = wbase[r * 32 + (lane & 15)];
            wreg[1][r] = wbase[r * 32 + 16 + (lane & 15)];
        }
    }

    f32x4 acc[4];
    #pragma unroll
    for (int i = 0; i < 4; ++i) { acc[i].x = 0; acc[i].y = 0; acc[i].z = 0; acc[i].w = 0; }

    const int mt2  = wv >> 1;          // stage-A tile row
    const int nt2b = (wv & 1) * 2;     // stage-A tile col base

    const float* xim = x + (size_t)img * 65536;
    const int r_st  = t >> 3;
    const int c4_st = t & 7;
    const float4* src = (const float4*)xim + r_st * 64 + c4_st;

    // prefetch chunk 0 into registers
    float4 pre[8];
    #pragma unroll
    for (int i = 0; i < 8; ++i) pre[i] = src[i * 8];

    // ---------------- forward: 8 chunks of 32 h-rows ----------------
    #pragma unroll 1
    for (int hc = 0; hc < 8; ++hc) {
        {   // registers -> LDS (split bf16, row-swizzle)
            #pragma unroll
            for (int i = 0; i < 8; ++i) {
                float4 vx = pre[i];
                int cc = (c4_st + i * 8) * 4;
                int idx = (r_st * 256 + cc) ^ ((r_st & 7) << 3);
                unsigned short h0,l0,h1,l1,h2,l2,h3,l3;
                split2(vx.x, h0, l0); split2(vx.y, h1, l1);
                split2(vx.z, h2, l2); split2(vx.w, h3, l3);
                short4v vh, vl;
                vh.x=(short)h0; vh.y=(short)h1; vh.z=(short)h2; vh.w=(short)h3;
                vl.x=(short)l0; vl.y=(short)l1; vl.z=(short)l2; vl.w=(short)l3;
                *(short4v*)&xs_hi[idx] = vh;
                *(short4v*)&xs_lo[idx] = vl;
            }
        }
        __syncthreads();
        if (hc < 7) {   // issue next chunk's loads; latency hides under MFMAs
            const float4* nsrc = src + (hc + 1) * 2048;
            #pragma unroll
            for (int i = 0; i < 8; ++i) pre[i] = nsrc[i * 8];
        }
        // stage A: Ywc(32x64) = xc @ B2, 2 tiles/wave
        f32x4 acc2[2];
        acc2[0].x=0; acc2[0].y=0; acc2[0].z=0; acc2[0].w=0;
        acc2[1].x=0; acc2[1].y=0; acc2[1].z=0; acc2[1].w=0;
        {
            const int mrow = mt2 * 16 + (lane & 15);
            const int kb = (lane >> 4) * 8;
            #pragma unroll
            for (int kt = 0; kt < 8; ++kt) {
                int aidx = (mrow * 256 + kt * 32 + kb) ^ ((mrow & 7) << 3);
                bf16x8 ah = *(const bf16x8*)&xs_hi[aidx];
                bf16x8 al = *(const bf16x8*)&xs_lo[aidx];
                #pragma unroll
                for (int q = 0; q < 2; ++q) {
                    int boff = ((kt * 4 + nt2b + q) * 64 + lane) * 8;
                    bf16x8 bh = *(const bf16x8*)&cst[C_B2H + boff];
                    bf16x8 bl = *(const bf16x8*)&cst[C_B2L + boff];
                    acc2[q] = MFMA16(ah, bh, acc2[q]);
                    acc2[q] = MFMA16(ah, bl, acc2[q]);
                    acc2[q] = MFMA16(al, bh, acc2[q]);
                }
            }
        }
        {   // Ywc -> YT[n][h'] (transposed, split); pack 4 rows per b64 write
            const int hbase = mt2 * 16 + (lane >> 4) * 4;
            #pragma unroll
            for (int q = 0; q < 2; ++q) {
                int n = (nt2b + q) * 16 + (lane & 15);
                int idx = (n * 32 + hbase) ^ ((n & 7) << 3);
                short4v vh, vl; unsigned short hh, ll;
                split2(acc2[q][0], hh, ll); vh.x=(short)hh; vl.x=(short)ll;
                split2(acc2[q][1], hh, ll); vh.y=(short)hh; vl.y=(short)ll;
                split2(acc2[q][2], hh, ll); vh.z=(short)hh; vl.z=(short)ll;
                split2(acc2[q][3], hh, ll); vh.w=(short)hh; vl.w=(short)ll;
                *(short4v*)&yt_hi[idx] = vh;
                *(short4v*)&yt_lo[idx] = vl;
            }
        }
        __syncthreads();
        {   // stage B: X-tiles (mt=wv, nt=0..3) += E1(k-chunk hc) @ Ywc
            const int aoff = ((hc * 4 + wv) * 64 + lane) * 8;
            bf16x8 c1h = *(const bf16x8*)&cst[C_C1H + aoff];
            bf16x8 c1l = *(const bf16x8*)&cst[C_C1L + aoff];
            bf16x8 s1h = *(const bf16x8*)&cst[C_S1H + aoff];
            bf16x8 s1l = *(const bf16x8*)&cst[C_S1L + aoff];
            bf16x8 snh = *(const bf16x8*)&cst[C_SNH + aoff];
            bf16x8 snl = *(const bf16x8*)&cst[C_SNL + aoff];
            const int kl = (lane >> 4) * 8;
            #pragma unroll
            for (int nt = 0; nt < 4; ++nt) {
                int nRe = (nt & 1) * 16 + (lane & 15);
                int nIm = 32 + nRe;
                int reIdx = (nRe * 32 + kl) ^ ((nRe & 7) << 3);
                int imIdx = (nIm * 32 + kl) ^ ((nIm & 7) << 3);
                bf16x8 brh = *(const bf16x8*)&yt_hi[reIdx];
                bf16x8 brl = *(const bf16x8*)&yt_lo[reIdx];
                bf16x8 bih = *(const bf16x8*)&yt_hi[imIdx];
                bf16x8 bil = *(const bf16x8*)&yt_lo[imIdx];
                if (nt < 2) {   // X_re = C1@Yr + S1@Yi
                    acc[nt] = MFMA16(c1h, brh, acc[nt]);
                    acc[nt] = MFMA16(c1h, brl, acc[nt]);
                    acc[nt] = MFMA16(c1l, brh, acc[nt]);
                    acc[nt] = MFMA16(s1h, bih, acc[nt]);
                    acc[nt] = MFMA16(s1h, bil, acc[nt]);
                    acc[nt] = MFMA16(s1l, bih, acc[nt]);
                } else {        // X_im = C1@Yi + (-S1)@Yr
                    acc[nt] = MFMA16(c1h, bih, acc[nt]);
                    acc[nt] = MFMA16(c1h, bil, acc[nt]);
                    acc[nt] = MFMA16(c1l, bih, acc[nt]);
                    acc[nt] = MFMA16(snh, brh, acc[nt]);
                    acc[nt] = MFMA16(snh, brl, acc[nt]);
                    acc[nt] = MFMA16(snl, brh, acc[nt]);
                }
            }
        }
        __syncthreads();
    }

    // ---------------- G = X*wsum -> GT (in-register, packed b64 writes) -----
    // thread holds X[s][.] for s=s0..s0+3: acc[j]=Xre(k2=j*16+l), acc[2+j]=Xim
    {
        unsigned short* GTh = lds;              // [64][128]
        unsigned short* GTl = lds + 8192;
        const int l15 = lane & 15;
        const int s0 = wv * 16 + (lane >> 4) * 4;
        #pragma unroll
        for (int j = 0; j < 2; ++j) {
            int k2 = j * 16 + l15;
            int col = s0 ^ ((k2 & 7) << 3);     // (s0+r)^swz == col+r (r<4)
            short4v grh, grl, gih, gil, ngh, ngl;
            #pragma unroll
            for (int r = 0; r < 4; ++r) {
                float xr = acc[j][r], xi = acc[2 + j][r];
                float wr = wreg[j][r].x, wi = wreg[j][r].y;
                float gr = xr * wr - xi * wi;
                float gi = xr * wi + xi * wr;
                unsigned short h1, l1, h2, l2;
                split2(gr, h1, l1); split2(gi, h2, l2);
                grh[r] = (short)h1; grl[r] = (short)l1;
                gih[r] = (short)h2; gil[r] = (short)l2;
                ngh[r] = (short)(h2 ^ 0x8000u); ngl[r] = (short)(l2 ^ 0x8000u);
            }
            *(short4v*)&GTh[k2 * 128 + col] = grh;            // Gr
            *(short4v*)&GTl[k2 * 128 + col] = grl;
            *(short4v*)&GTh[(32 + k2) * 128 + col] = gih;     // Gi
            *(short4v*)&GTl[(32 + k2) * 128 + col] = gil;
            *(short4v*)&GTh[k2 * 128 + 64 + col] = ngh;       // -Gi
            *(short4v*)&GTl[k2 * 128 + 64 + col] = ngl;
            *(short4v*)&GTh[(32 + k2) * 128 + 64 + col] = grh; // Gr
            *(short4v*)&GTl[(32 + k2) * 128 + 64 + col] = grl;
        }
    }
    __syncthreads();

    // ---------------- phase 1: T = A1 @ Gbig ----------------
    unsigned short* GTh = lds;
    unsigned short* GTl = lds + 8192;
    f32x4 Tacc[4][4];
    #pragma unroll
    for (int a = 0; a < 4; ++a)
        #pragma unroll
        for (int b = 0; b < 4; ++b) { Tacc[a][b].x=0; Tacc[a][b].y=0; Tacc[a][b].z=0; Tacc[a][b].w=0; }
    {
        const int kb = (lane >> 4) * 8;
        #pragma unroll
        for (int kt = 0; kt < 4; ++kt) {
            bf16x8 bh[4], bl[4];
            #pragma unroll
            for (int nt = 0; nt < 4; ++nt) {
                int n = nt * 16 + (lane & 15);
                int idx = (n * 128 + kt * 32 + kb) ^ ((n & 7) << 3);
                bh[nt] = *(const bf16x8*)&GTh[idx];
                bl[nt] = *(const bf16x8*)&GTl[idx];
            }
            #pragma unroll
            for (int mi = 0; mi < 4; ++mi) {
                int aoff = ((kt * 16 + 4 * wv + mi) * 64 + lane) * 8;
                bf16x8 ah = *(const bf16x8*)&cst[C_A1H + aoff];
                bf16x8 al = *(const bf16x8*)&cst[C_A1L + aoff];
                #pragma unroll
                for (int nt = 0; nt < 4; ++nt) {
                    Tacc[mi][nt] = MFMA16(ah, bh[nt], Tacc[mi][nt]);
                    Tacc[mi][nt] = MFMA16(ah, bl[nt], Tacc[mi][nt]);
                    Tacc[mi][nt] = MFMA16(al, bh[nt], Tacc[mi][nt]);
                }
            }
        }
    }
    __syncthreads();    // all GT reads done before overwriting with T

    unsigned short* Th = lds;               // [256][64]
    unsigned short* Tl = lds + 16384;
    {   // write T (split) to LDS [m][k], row-swizzled
        #pragma unroll
        for (int mi = 0; mi < 4; ++mi) {
            int m0 = (4 * wv + mi) * 16 + (lane >> 4) * 4;
            #pragma unroll
            for (int nt = 0; nt < 4; ++nt) {
                int k = nt * 16 + (lane & 15);
                #pragma unroll
                for (int r = 0; r < 4; ++r) {
                    int m = m0 + r;
                    int idx = (m * 64 + k) ^ ((m & 7) << 3);
                    unsigned short hh, ll; split2(Tacc[mi][nt][r], hh, ll);
                    Th[idx] = hh; Tl[idx] = ll;
                }
            }
        }
    }
    __syncthreads();

    // ---------------- phase 2: out = T @ D, 4 row-strips ----------------
    float* oim = out + (size_t)img * 65536;
    const int kb2 = (lane >> 4) * 8;
    #pragma unroll 1
    for (int strip = 0; strip < 4; ++strip) {
        f32x4 oacc[4][4];
        #pragma unroll
        for (int a = 0; a < 4; ++a)
            #pragma unroll
            for (int b = 0; b < 4; ++b) { oacc[a][b].x=0; oacc[a][b].y=0; oacc[a][b].z=0; oacc[a][b].w=0; }
        #pragma unroll
        for (int kt = 0; kt < 2; ++kt) {
            bf16x8 ah[4], al[4];
            #pragma unroll
            for (int mi = 0; mi < 4; ++mi) {
                int m = (strip * 4 + mi) * 16 + (lane & 15);
                int idx = (m * 64 + kt * 32 + kb2) ^ ((m & 7) << 3);
                ah[mi] = *(const bf16x8*)&Th[idx];
                al[mi] = *(const bf16x8*)&Tl[idx];
            }
            #pragma unroll
            for (int ni = 0; ni < 4; ++ni) {
                int boff = ((kt * 16 + 4 * wv + ni) * 64 + lane) * 8;
                bf16x8 bh = *(const bf16x8*)&cst[C_DH + boff];
                bf16x8 bl = *(const bf16x8*)&cst[C_DL + boff];
                #pragma unroll
                for (int mi = 0; mi < 4; ++mi) {
                    oacc[mi][ni] = MFMA16(ah[mi], bh, oacc[mi][ni]);
                    oacc[mi][ni] = MFMA16(ah[mi], bl, oacc[mi][ni]);
                    oacc[mi][ni] = MFMA16(al[mi], bh, oacc[mi][ni]);
                }
            }
        }
        #pragma unroll
        for (int mi = 0; mi < 4; ++mi) {
            int h = strip * 64 + mi * 16 + (lane >> 4) * 4;
            #pragma unroll
            for (int ni = 0; ni < 4; ++ni) {
                int wc = (4 * wv + ni) * 16 + (lane & 15);
                #pragma unroll
                for (int r = 0; r < 4; ++r)
                    oim[(size_t)(h + r) * 256 + wc] = oacc[mi][ni][r];
            }
        }
    }
}

// ---------------------------------------------------------------------------
extern "C" void kernel_launch(void* const* d_in, const int* in_sizes, int n_in,
                              void* d_out, int out_size, void* d_ws, size_t ws_size,
                              hipStream_t stream) {
    const float* x   = (const float*)d_in[0];
    const float* w1r = (const float*)d_in[1];
    const float* w1i = (const float*)d_in[2];
    const float* w2r = (const float*)d_in[3];
    const float* w2i = (const float*)d_in[4];
    float* out = (float*)d_out;

    char* ws = (char*)d_ws;
    float4* part = (float4*)ws;                             // 8 MiB partials (dead after reduce)
    float2* s1 = (float2*)(ws + 16777216);                  // 512 KiB
    float2* s2 = (float2*)(ws + 16777216 + 524288);         // 512 KiB
    unsigned short* cst = (unsigned short*)(ws + 17825792); // 448 KiB prefrag consts

    hipLaunchKernelGGL(const_kernel, dim3(448), dim3(256), 0, stream, cst);
    hipLaunchKernelGGL(wsum_part, dim3(512), dim3(256), 0, stream,
                       w1r, w1i, w2r, w2i, part);
    hipLaunchKernelGGL(wsum_reduce, dim3(64), dim3(256), 0, stream,
                       part, (float4*)s1, (float4*)s2);
    hipLaunchKernelGGL(fused_kernel, dim3(1024), dim3(256), 0, stream,
                       x, s1, s2, out, cst);
}